// Round 1
// baseline (688.744 us; speedup 1.0000x reference)
//
#include <hip/hip_runtime.h>
#include <stdint.h>
#include <stddef.h>

#define BATCH 512
#define RSZ   196
#define DV    1024
#define DH    512
#define DA    256
#define MTOT  (BATCH * RSZ)   // 100352 = 64 * 1568

typedef short short8 __attribute__((ext_vector_type(8)));
typedef float f32x4 __attribute__((ext_vector_type(4)));

static __device__ __forceinline__ short f2bf(float f) {
    union { float f; unsigned u; } x; x.f = f;
    unsigned r = x.u + 0x7fffu + ((x.u >> 16) & 1u);  // RNE
    return (short)(r >> 16);
}

// ---------------- kernel 0: Wv [K=1024][N=256] fp32 -> WvT [N=256][K=1024] bf16
__global__ void k_prep_wvt(const float* __restrict__ Wv, short* __restrict__ WvT) {
    int idx = blockIdx.x * 256 + threadIdx.x;   // 262144 total
    int k = idx >> 8;
    int n = idx & 255;
    WvT[n * DV + k] = f2bf(Wv[idx]);
}

// ---------------- kernel 1: H[b][a] = hs[b]@Wh[:,a] + bh[a] + bv[a]  (fp32)
__global__ __launch_bounds__(256) void k_hproj(const float* __restrict__ hs,
                                               const float* __restrict__ Wh,
                                               const float* __restrict__ bh,
                                               const float* __restrict__ bv,
                                               float* __restrict__ H) {
    __shared__ float sh[DH];
    int b = blockIdx.x, a = threadIdx.x;
    sh[a]       = hs[b * DH + a];
    sh[a + 256] = hs[b * DH + 256 + a];
    __syncthreads();
    float acc = 0.f;
#pragma unroll 8
    for (int k = 0; k < DH; ++k) acc += sh[k] * Wh[k * DA + a];
    H[b * DA + a] = acc + bh[a] + bv[a];
}

// ---------------- kernel 2: fused v_proj GEMM (bf16 MFMA) + relu + dot(Wa) -> scores
#define BK  64
#define LDA 72   // padded LDS row stride in bf16 units (2-way bank aliasing = free)

__global__ __launch_bounds__(256) void k_scores(const float* __restrict__ vf,
                                                const short* __restrict__ WvT,
                                                const float* __restrict__ H,
                                                const float* __restrict__ Wa,
                                                const float* __restrict__ ba,
                                                float* __restrict__ scores) {
    __shared__ short As[64 * LDA];
    __shared__ short Bs[256 * LDA];
    __shared__ float sWa[DA];
    __shared__ float sH[2][DA];
    __shared__ float red[64][4];

    const int tid  = threadIdx.x;
    const int lane = tid & 63;
    const int w    = tid >> 6;        // wave 0..3 -> col chunk w*64
    const int ln   = lane & 15;
    const int q    = lane >> 4;       // quad 0..3
    const int m0   = blockIdx.x * 64;
    const int b0   = m0 / RSZ;
    const int b1   = (m0 + 63) / RSZ;

    sWa[tid]   = Wa[tid];
    sH[0][tid] = H[b0 * DA + tid];
    sH[1][tid] = H[b1 * DA + tid];

    f32x4 acc[4][4];
#pragma unroll
    for (int i = 0; i < 4; ++i)
#pragma unroll
        for (int j = 0; j < 4; ++j) acc[i][j] = (f32x4){0.f, 0.f, 0.f, 0.f};

    const int ar = tid >> 2;          // A-stage row 0..63
    const int ac = (tid & 3) * 16;    // A-stage col base within BK
    const float* aptr = vf + (size_t)(m0 + ar) * DV + ac;

    for (int kt = 0; kt < DV; kt += BK) {
        // ---- stage A tile (64 x 64) fp32 -> bf16
        float4 av0 = *(const float4*)(aptr + kt + 0);
        float4 av1 = *(const float4*)(aptr + kt + 4);
        float4 av2 = *(const float4*)(aptr + kt + 8);
        float4 av3 = *(const float4*)(aptr + kt + 12);
        short8 p0 = { f2bf(av0.x), f2bf(av0.y), f2bf(av0.z), f2bf(av0.w),
                      f2bf(av1.x), f2bf(av1.y), f2bf(av1.z), f2bf(av1.w) };
        short8 p1 = { f2bf(av2.x), f2bf(av2.y), f2bf(av2.z), f2bf(av2.w),
                      f2bf(av3.x), f2bf(av3.y), f2bf(av3.z), f2bf(av3.w) };
        *(short8*)&As[ar * LDA + ac + 0] = p0;
        *(short8*)&As[ar * LDA + ac + 8] = p1;
        // ---- stage B tile (256 x 64) bf16, already [n][k]
#pragma unroll
        for (int j = 0; j < 8; ++j) {
            int c  = tid + 256 * j;     // 0..2047 chunk id (16B chunks)
            int n  = c >> 3;
            int ko = (c & 7) * 8;
            *(short8*)&Bs[n * LDA + ko] = *(const short8*)(WvT + n * DV + kt + ko);
        }
        __syncthreads();
#pragma unroll
        for (int kk = 0; kk < 2; ++kk) {
            short8 afr[4], bfr[4];
#pragma unroll
            for (int i = 0; i < 4; ++i)
                afr[i] = *(short8*)&As[(i * 16 + ln) * LDA + kk * 32 + q * 8];
#pragma unroll
            for (int j = 0; j < 4; ++j)
                bfr[j] = *(short8*)&Bs[(w * 64 + j * 16 + ln) * LDA + kk * 32 + q * 8];
#pragma unroll
            for (int i = 0; i < 4; ++i)
#pragma unroll
                for (int j = 0; j < 4; ++j)
                    acc[i][j] = __builtin_amdgcn_mfma_f32_16x16x32_bf16(
                        afr[i], bfr[j], acc[i][j], 0, 0, 0);
        }
        __syncthreads();
    }

    // ---- epilogue: relu(acc + H) * Wa, reduce over the 256 cols
#pragma unroll
    for (int i = 0; i < 4; ++i) {
#pragma unroll
        for (int r = 0; r < 4; ++r) {
            int row = i * 16 + q * 4 + r;
            int m   = m0 + row;
            int bb  = m / RSZ;
            const float* hrow = sH[(bb == b0) ? 0 : 1];
            float p = 0.f;
#pragma unroll
            for (int j = 0; j < 4; ++j) {
                int a   = w * 64 + j * 16 + ln;
                float v = acc[i][j][r] + hrow[a];
                p += fmaxf(v, 0.f) * sWa[a];
            }
            p += __shfl_xor(p, 1);
            p += __shfl_xor(p, 2);
            p += __shfl_xor(p, 4);
            p += __shfl_xor(p, 8);
            if (ln == 0) red[row][w] = p;
        }
    }
    __syncthreads();
    if (tid < 64) {
        float s = red[tid][0] + red[tid][1] + red[tid][2] + red[tid][3] + ba[0];
        scores[m0 + tid] = s;
    }
}

// ---------------- kernel 3: softmax over R=196 per batch (one wave per b)
__global__ __launch_bounds__(64) void k_softmax(const float* __restrict__ scores,
                                                float* __restrict__ att) {
    int b = blockIdx.x, t = threadIdx.x;
    float v[4], e[4];
    float m = -1e30f;
#pragma unroll
    for (int j = 0; j < 4; ++j) {
        int idx = j * 64 + t;
        v[j] = (idx < RSZ) ? scores[b * RSZ + idx] : -1e30f;
        m = fmaxf(m, v[j]);
    }
#pragma unroll
    for (int mk = 32; mk >= 1; mk >>= 1) m = fmaxf(m, __shfl_xor(m, mk));
    float s = 0.f;
#pragma unroll
    for (int j = 0; j < 4; ++j) {
        int idx = j * 64 + t;
        e[j] = (idx < RSZ) ? expf(v[j] - m) : 0.f;
        s += e[j];
    }
#pragma unroll
    for (int mk = 32; mk >= 1; mk >>= 1) s += __shfl_xor(s, mk);
    float inv = 1.f / s;
#pragma unroll
    for (int j = 0; j < 4; ++j) {
        int idx = j * 64 + t;
        if (idx < RSZ) att[b * RSZ + idx] = e[j] * inv;
    }
}

// ---------------- kernel 4: out[b][d] = sum_r att[b][r] * vf[b][r][d]  (fp32, HBM-bound)
__global__ __launch_bounds__(256) void k_attout(const float* __restrict__ vf,
                                                const float* __restrict__ att,
                                                float* __restrict__ out) {
    __shared__ float satt[RSZ];
    int b = blockIdx.x, t = threadIdx.x;
    if (t < RSZ) satt[t] = att[b * RSZ + t];
    __syncthreads();
    const float4* vp = (const float4*)(vf + (size_t)b * RSZ * DV) + t;  // cols 4t..4t+3
    float4 acc = {0.f, 0.f, 0.f, 0.f};
    for (int r = 0; r < RSZ; r += 4) {   // 196 = 4*49
        float4 v0 = vp[(r + 0) * (DV / 4)];
        float4 v1 = vp[(r + 1) * (DV / 4)];
        float4 v2 = vp[(r + 2) * (DV / 4)];
        float4 v3 = vp[(r + 3) * (DV / 4)];
        float a0 = satt[r], a1 = satt[r + 1], a2 = satt[r + 2], a3 = satt[r + 3];
        acc.x += a0 * v0.x + a1 * v1.x + a2 * v2.x + a3 * v3.x;
        acc.y += a0 * v0.y + a1 * v1.y + a2 * v2.y + a3 * v3.y;
        acc.z += a0 * v0.z + a1 * v1.z + a2 * v2.z + a3 * v3.z;
        acc.w += a0 * v0.w + a1 * v1.w + a2 * v2.w + a3 * v3.w;
    }
    ((float4*)(out + (size_t)b * DV))[t] = acc;
}

extern "C" void kernel_launch(void* const* d_in, const int* in_sizes, int n_in,
                              void* d_out, int out_size, void* d_ws, size_t ws_size,
                              hipStream_t stream) {
    const float* vf = (const float*)d_in[0];   // [512,196,1024]
    const float* hs = (const float*)d_in[1];   // [512,512]
    const float* Wv = (const float*)d_in[2];   // [1024,256]
    const float* bv = (const float*)d_in[3];   // [256]
    const float* Wh = (const float*)d_in[4];   // [512,256]
    const float* bh = (const float*)d_in[5];   // [256]
    const float* Wa = (const float*)d_in[6];   // [256]
    const float* ba = (const float*)d_in[7];   // scalar
    float* out = (float*)d_out;                // [512,1024]

    char* ws = (char*)d_ws;
    short* WvT    = (short*)(ws);                       // 512 KB
    float* H      = (float*)(ws + (512 << 10));         // 512 KB
    float* scores = (float*)(ws + (1024 << 10));        // 392 KB
    float* att    = (float*)(ws + (1536 << 10));        // 392 KB

    k_prep_wvt<<<1024, 256, 0, stream>>>(Wv, WvT);
    k_hproj<<<BATCH, 256, 0, stream>>>(hs, Wh, bh, bv, H);
    k_scores<<<MTOT / 64, 256, 0, stream>>>(vf, WvT, H, Wa, ba, scores);
    k_softmax<<<BATCH, 64, 0, stream>>>(scores, att);
    k_attout<<<BATCH, 256, 0, stream>>>(vf, att, out);
}